// Round 9
// baseline (541.873 us; speedup 1.0000x reference)
//
#include <hip/hip_runtime.h>

#define B_   32
#define S_   8192
#define C_   256   // KD == QD == 256
#define LD_  256
#define H_   8
#define SD_  32
#define CH   64    // keys per chunk
#define NCH  (S_ / CH)   // 128 chunks per batch

// workspace layout (floats)
#define WS_QK    0
#define WS_LSUM  (WS_QK + B_*H_*C_)
#define WS_CTX   (WS_LSUM + B_*H_)
#define WS_TOTAL (WS_CTX + B_*H_*C_)

// ---------------------------------------------------------------------------
// Kernel A: qk[b,h,c] = (1/sqrt(SD)) * sum_d (query[b]·Wq)[h*SD+d] * Wk[h*SD+d, c]
// ---------------------------------------------------------------------------
__global__ __launch_bounds__(256) void proj_qk(const float* __restrict__ query,
                                               const float* __restrict__ Wq,
                                               const float* __restrict__ Wk,
                                               float* __restrict__ ws) {
    const int b = blockIdx.x, t = threadIdx.x;
    __shared__ float qry[C_];
    __shared__ float qv[LD_];
    qry[t] = query[b * C_ + t];
    __syncthreads();
    {
        const float* wr = Wq + t * C_;
        float a = 0.f;
        for (int c = 0; c < C_; c += 4) {
            float4 w = *(const float4*)(wr + c);
            float4 x = *(const float4*)(qry + c);
            a = fmaf(w.x, x.x, fmaf(w.y, x.y, fmaf(w.z, x.z, fmaf(w.w, x.w, a))));
        }
        qv[t] = a;
    }
    __syncthreads();
    const float scale = 0.17677669529663687f;  // 1/sqrt(32)
    float* qkb = ws + WS_QK + b * H_ * C_;
    #pragma unroll
    for (int h = 0; h < H_; h++) {
        float a = 0.f;
        #pragma unroll 8
        for (int d = 0; d < SD_; d++) {
            a = fmaf(qv[h * SD_ + d], Wk[(h * SD_ + d) * C_ + t], a);
        }
        qkb[h * C_ + t] = a * scale;
    }
}

// ---------------------------------------------------------------------------
// Kernel B (restructured for occupancy): grid (128,32) = 4096 blocks, CH=64.
// LDS 18.5KB -> 8 blocks/CU -> occupancy cap 100% (was 50% at round-4's 40%).
// Phase 1: thread (s = t&63, q = t>>6) dots 64 channels x 8 heads (q is
//   wave-uniform -> qk LDS reads broadcast). Partials to LDS [q][h][s]
//   (lanes vary s -> conflict-free).
// Reduce: wave g sums partials for heads 2g,2g+1, applies mask+exp, stores
//   unmasked (coalesced NT) and p_t[s][h]; lsum via 64-lane shfl_xor
//   butterfly + 1 atomic per wave.
// Phase 3: thread t = channel; fully coalesced column reads (whole 256-float
//   row per wave-instr), p broadcast as 2x float4; atomics into ctxsum.
// ---------------------------------------------------------------------------
__global__ __launch_bounds__(256) void attn_pass(const float* __restrict__ keys,
                                                 const float* __restrict__ pmask,
                                                 const float* __restrict__ ws_qk,
                                                 float* __restrict__ lsum,
                                                 float* __restrict__ ctxsum,
                                                 float* __restrict__ out_unmasked) {
    const int b = blockIdx.y, ch = blockIdx.x, t = threadIdx.x;
    const int s0 = ch * CH;
    __shared__ float qk_s[H_][C_];      // 8 KB
    __shared__ float part[4][H_][CH];   // 8 KB  [q][h][s]
    __shared__ float p_t[CH][H_];       // 2 KB  [s][h]
    __shared__ float pm_s[CH];

    // stage qk (2048 floats = 512 float4, 2 per thread) + mask
    {
        const float4* src = (const float4*)(ws_qk + b * H_ * C_);
        float4* dst = (float4*)&qk_s[0][0];
        dst[t]       = src[t];
        dst[t + 256] = src[t + 256];
    }
    if (t < CH) pm_s[t] = __builtin_nontemporal_load(pmask + b * S_ + s0 + t);
    __syncthreads();

    // ---- phase 1: split-channel dot ----
    {
        const int sl = t & 63, q = t >> 6;          // q wave-uniform
        const float* krow = keys + ((size_t)b * S_ + s0 + sl) * C_ + q * 64;
        const float* qrow = &qk_s[0][q * 64];       // head h at qrow + h*C_
        float acc0 = 0.f, acc1 = 0.f, acc2 = 0.f, acc3 = 0.f;
        float acc4 = 0.f, acc5 = 0.f, acc6 = 0.f, acc7 = 0.f;
        #pragma unroll
        for (int c = 0; c < 64; c += 4) {
            float4 kv = *(const float4*)(krow + c);
            float4 w0 = *(const float4*)(qrow + 0 * C_ + c);
            float4 w1 = *(const float4*)(qrow + 1 * C_ + c);
            float4 w2 = *(const float4*)(qrow + 2 * C_ + c);
            float4 w3 = *(const float4*)(qrow + 3 * C_ + c);
            float4 w4 = *(const float4*)(qrow + 4 * C_ + c);
            float4 w5 = *(const float4*)(qrow + 5 * C_ + c);
            float4 w6 = *(const float4*)(qrow + 6 * C_ + c);
            float4 w7 = *(const float4*)(qrow + 7 * C_ + c);
            acc0 = fmaf(kv.x, w0.x, fmaf(kv.y, w0.y, fmaf(kv.z, w0.z, fmaf(kv.w, w0.w, acc0))));
            acc1 = fmaf(kv.x, w1.x, fmaf(kv.y, w1.y, fmaf(kv.z, w1.z, fmaf(kv.w, w1.w, acc1))));
            acc2 = fmaf(kv.x, w2.x, fmaf(kv.y, w2.y, fmaf(kv.z, w2.z, fmaf(kv.w, w2.w, acc2))));
            acc3 = fmaf(kv.x, w3.x, fmaf(kv.y, w3.y, fmaf(kv.z, w3.z, fmaf(kv.w, w3.w, acc3))));
            acc4 = fmaf(kv.x, w4.x, fmaf(kv.y, w4.y, fmaf(kv.z, w4.z, fmaf(kv.w, w4.w, acc4))));
            acc5 = fmaf(kv.x, w5.x, fmaf(kv.y, w5.y, fmaf(kv.z, w5.z, fmaf(kv.w, w5.w, acc5))));
            acc6 = fmaf(kv.x, w6.x, fmaf(kv.y, w6.y, fmaf(kv.z, w6.z, fmaf(kv.w, w6.w, acc6))));
            acc7 = fmaf(kv.x, w7.x, fmaf(kv.y, w7.y, fmaf(kv.z, w7.z, fmaf(kv.w, w7.w, acc7))));
        }
        part[q][0][sl] = acc0; part[q][1][sl] = acc1;
        part[q][2][sl] = acc2; part[q][3][sl] = acc3;
        part[q][4][sl] = acc4; part[q][5][sl] = acc5;
        part[q][6][sl] = acc6; part[q][7][sl] = acc7;
    }
    __syncthreads();

    // ---- reduce + mask + exp + unmasked-out + lsum ----
    {
        const int s = t & 63, g = t >> 6;           // heads 2g, 2g+1
        const int h0 = 2 * g, h1 = 2 * g + 1;
        const float pen = (1.0f - pm_s[s]) * -10000.0f;
        float d0 = part[0][h0][s] + part[1][h0][s] + part[2][h0][s] + part[3][h0][s];
        float d1 = part[0][h1][s] + part[1][h1][s] + part[2][h1][s] + part[3][h1][s];
        float* ub = out_unmasked + (size_t)(b * H_) * S_ + s0 + s;
        __builtin_nontemporal_store(d0, ub + (size_t)h0 * S_);
        __builtin_nontemporal_store(d1, ub + (size_t)h1 * S_);
        float p0 = __expf(d0 + pen);
        float p1 = __expf(d1 + pen);
        p_t[s][h0] = p0;
        p_t[s][h1] = p1;
        float r0 = p0, r1 = p1;
        #pragma unroll
        for (int off = 32; off > 0; off >>= 1) {
            r0 += __shfl_xor(r0, off);
            r1 += __shfl_xor(r1, off);
        }
        if (s == 0) {
            atomicAdd(&lsum[b * H_ + h0], r0);
            atomicAdd(&lsum[b * H_ + h1], r1);
        }
    }
    __syncthreads();

    // ---- phase 3: ctx accumulation, lane = channel, fully coalesced ----
    {
        float f0 = 0.f, f1 = 0.f, f2 = 0.f, f3 = 0.f;
        float f4 = 0.f, f5 = 0.f, f6 = 0.f, f7 = 0.f;
        const float* kcol = keys + ((size_t)b * S_ + s0) * C_ + t;
        #pragma unroll 4
        for (int s = 0; s < CH; ++s) {
            float kv = kcol[(size_t)s * C_];          // 256 consecutive floats/instr
            float4 pA = *(const float4*)&p_t[s][0];   // broadcast
            float4 pB = *(const float4*)&p_t[s][4];
            f0 = fmaf(pA.x, kv, f0); f1 = fmaf(pA.y, kv, f1);
            f2 = fmaf(pA.z, kv, f2); f3 = fmaf(pA.w, kv, f3);
            f4 = fmaf(pB.x, kv, f4); f5 = fmaf(pB.y, kv, f5);
            f6 = fmaf(pB.z, kv, f6); f7 = fmaf(pB.w, kv, f7);
        }
        float* cb = ctxsum + (size_t)b * H_ * C_ + t;
        atomicAdd(cb + 0 * C_, f0); atomicAdd(cb + 1 * C_, f1);
        atomicAdd(cb + 2 * C_, f2); atomicAdd(cb + 3 * C_, f3);
        atomicAdd(cb + 4 * C_, f4); atomicAdd(cb + 5 * C_, f5);
        atomicAdd(cb + 6 * C_, f6); atomicAdd(cb + 7 * C_, f7);
    }
}

// ---------------------------------------------------------------------------
// Kernel C: ctxn = ctx/L; out[l] = Wv[l,:]·ctxn[h(l),:]; unified = Wu·out + bu
// ---------------------------------------------------------------------------
__global__ __launch_bounds__(256) void finalize(const float* __restrict__ Wv,
                                                const float* __restrict__ Wu,
                                                const float* __restrict__ bu,
                                                const float* __restrict__ lsum,
                                                const float* __restrict__ ctxsum,
                                                float* __restrict__ out_unified) {
    const int b = blockIdx.x, t = threadIdx.x;
    __shared__ float ctxn[H_ * C_];
    __shared__ float outv[LD_];
    __shared__ float linv[H_];
    if (t < H_) linv[t] = 1.0f / lsum[b * H_ + t];
    __syncthreads();
    for (int i = t; i < H_ * C_; i += 256)
        ctxn[i] = ctxsum[(size_t)b * H_ * C_ + i] * linv[i >> 8];
    __syncthreads();
    {
        const float* wr = Wv + t * C_;
        const float* cx = ctxn + (t >> 5) * C_;
        float a = 0.f;
        for (int c = 0; c < C_; c += 4) {
            float4 w = *(const float4*)(wr + c);
            float4 x = *(const float4*)(cx + c);
            a = fmaf(w.x, x.x, fmaf(w.y, x.y, fmaf(w.z, x.z, fmaf(w.w, x.w, a))));
        }
        outv[t] = a;
    }
    __syncthreads();
    {
        const float* wr = Wu + t * C_;
        float a = bu[t];
        for (int c = 0; c < C_; c += 4) {
            float4 w = *(const float4*)(wr + c);
            float4 x = *(const float4*)(outv + c);
            a = fmaf(w.x, x.x, fmaf(w.y, x.y, fmaf(w.z, x.z, fmaf(w.w, x.w, a))));
        }
        out_unified[b * LD_ + t] = a;
    }
}

extern "C" void kernel_launch(void* const* d_in, const int* in_sizes, int n_in,
                              void* d_out, int out_size, void* d_ws, size_t ws_size,
                              hipStream_t stream) {
    const float* query = (const float*)d_in[0];
    const float* keys  = (const float*)d_in[1];
    const float* pmask = (const float*)d_in[2];
    const float* Wq    = (const float*)d_in[3];
    const float* Wk    = (const float*)d_in[4];
    const float* Wv    = (const float*)d_in[5];
    const float* Wu    = (const float*)d_in[6];
    const float* bu    = (const float*)d_in[7];

    float* out          = (float*)d_out;
    float* out_unified  = out;              // 32*256 floats
    float* out_unmasked = out + B_ * LD_;   // 32*8*8192 floats
    float* ws           = (float*)d_ws;

    // zero the accumulators (ws is re-poisoned to 0xAA before every launch)
    hipMemsetAsync(ws + WS_LSUM, 0, (size_t)(B_ * H_ + B_ * H_ * C_) * sizeof(float), stream);

    proj_qk<<<B_, 256, 0, stream>>>(query, Wq, Wk, ws);

    dim3 gridB(NCH, B_);
    attn_pass<<<gridB, 256, 0, stream>>>(keys, pmask, ws + WS_QK,
                                         ws + WS_LSUM, ws + WS_CTX, out_unmasked);

    finalize<<<B_, 256, 0, stream>>>(Wv, Wu, bu, ws + WS_LSUM, ws + WS_CTX, out_unified);
}

// Round 14
// 482.431 us; speedup vs baseline: 1.1232x; 1.1232x over previous
//
#include <hip/hip_runtime.h>

#define B_   32
#define S_   8192
#define C_   256   // KD == QD == 256
#define LD_  256
#define H_   8
#define SD_  32
#define CH   32                 // keys per chunk (LDS tile rows)
#define NCHUNK (S_ / CH)        // 256 chunks per batch
#define BPB  32                 // blocks per batch
#define CPB  (NCHUNK / BPB)     // 8 chunks per block (persistent)

// workspace layout (floats)
#define WS_QK    0
#define WS_LSUM  (WS_QK + B_*H_*C_)
#define WS_CTX   (WS_LSUM + B_*H_)

// ---------------------------------------------------------------------------
// Kernel A: qk[b,h,c] = (1/sqrt(SD)) * sum_d (query[b]·Wq)[h*SD+d] * Wk[h*SD+d, c]
// ---------------------------------------------------------------------------
__global__ __launch_bounds__(256) void proj_qk(const float* __restrict__ query,
                                               const float* __restrict__ Wq,
                                               const float* __restrict__ Wk,
                                               float* __restrict__ ws) {
    const int b = blockIdx.x, t = threadIdx.x;
    __shared__ float qry[C_];
    __shared__ float qv[LD_];
    qry[t] = query[b * C_ + t];
    __syncthreads();
    {
        const float* wr = Wq + t * C_;
        float a = 0.f;
        for (int c = 0; c < C_; c += 4) {
            float4 w = *(const float4*)(wr + c);
            float4 x = *(const float4*)(qry + c);
            a = fmaf(w.x, x.x, fmaf(w.y, x.y, fmaf(w.z, x.z, fmaf(w.w, x.w, a))));
        }
        qv[t] = a;
    }
    __syncthreads();
    const float scale = 0.17677669529663687f;  // 1/sqrt(32)
    float* qkb = ws + WS_QK + b * H_ * C_;
    #pragma unroll
    for (int h = 0; h < H_; h++) {
        float a = 0.f;
        #pragma unroll 8
        for (int d = 0; d < SD_; d++) {
            a = fmaf(qv[h * SD_ + d], Wk[(h * SD_ + d) * C_ + t], a);
        }
        qkb[h * C_ + t] = a * scale;
    }
}

// ---------------------------------------------------------------------------
// Kernel B v5 (LDS-staged single-read): 1024 persistent blocks, 8 chunks each.
// Round-9 counters: occupancy 78% yet 232us, FETCH 1.84x keys, VALU 10% ->
// scattered per-lane global reads + L3-missing phase-3 re-read were the cost.
// Now: stage chunk (32 rows x 1KB) into LDS with fully-coalesced row loads
// (keys read from HBM EXACTLY once; every fetched line fully consumed by its
// own instruction -> FETCH independent of cache behavior), both dot and ctx
// phases read LDS. tile rows padded +1 float2 (stride 258 dwords) -> phase-1
// b64 reads ~2-4-way aliased (hidden under VALU), phase-3 4-way. ctx/lsum
// accumulate in REGISTERS across chunks; one reduce + atomic burst per block.
// ---------------------------------------------------------------------------
__global__ __launch_bounds__(256, 2) void attn_pass(const float* __restrict__ keys,
                                                    const float* __restrict__ pmask,
                                                    const float* __restrict__ ws_qk,
                                                    float* __restrict__ lsum,
                                                    float* __restrict__ ctxsum,
                                                    float* __restrict__ out_unmasked) {
    const int b = blockIdx.x >> 5, bp = blockIdx.x & 31, t = threadIdx.x;
    __shared__ float2 tile2[CH][129];     // 33 KB: [s][c2], ch = (2c2, 2c2+1)
    __shared__ float  qk_s[H_ * C_];      // 8 KB
    __shared__ float  part[8][H_][CH];    // 8 KB: [c-slice][h][s]; reused as sc[8][256] in epilogue
    __shared__ float  p_t[CH][H_];        // 1 KB: [s][h], rows 32B-aligned

    // block-start: stage qk into LDS (coalesced, once)
    {
        const float4* src = (const float4*)(ws_qk + b * H_ * C_);
        float4* dst = (float4*)qk_s;
        dst[t]       = src[t];
        dst[t + 256] = src[t + 256];
    }

    // persistent accumulators
    float ctx_acc[H_][2];
    #pragma unroll
    for (int h = 0; h < H_; h++) { ctx_acc[h][0] = 0.f; ctx_acc[h][1] = 0.f; }
    float lsum_reg = 0.f;

    // thread maps
    const int st_row = t >> 3, st_j = t & 7;     // stage: 8 threads per row
    const int p1_sl = t & 31, p1_q = t >> 5;     // phase1: key sl, 32-ch slice q
    const int rd_s = t & 31, rd_g = t >> 5;      // reduce: key s, head g
    const int p3_c2 = t & 127, p3_sg = t >> 7;   // phase3: ch-pair c2, s-half sg

    for (int i = 0; i < CPB; i++) {
        const int s0 = (bp + BPB * i) * CH;
        __syncthreads();   // prev iter's phase-3 done with tile2/p_t (and qk_s staged, iter 0)

        // ---- stage: coalesced global -> LDS, keys' ONLY read ----
        {
            const float4* g = (const float4*)(keys + ((size_t)b * S_ + s0 + st_row) * C_);
            #pragma unroll
            for (int k = 0; k < 8; k++) {
                const int f4 = st_j + 8 * k;
                float4 v = g[f4];
                tile2[st_row][2 * f4]     = make_float2(v.x, v.y);
                tile2[st_row][2 * f4 + 1] = make_float2(v.z, v.w);
            }
        }
        __syncthreads();

        // ---- phase 1: partial dots, 8 heads over a 32-ch slice ----
        {
            float2 kvr[16];
            const float2* kr = &tile2[p1_sl][p1_q * 16];
            #pragma unroll
            for (int j = 0; j < 16; j++) kvr[j] = kr[j];   // ds_read_b64
            #pragma unroll
            for (int h = 0; h < H_; h++) {
                float a = 0.f;
                #pragma unroll
                for (int c4 = 0; c4 < 8; c4++) {
                    float4 qv = *(const float4*)(qk_s + h * C_ + p1_q * 32 + 4 * c4);  // ~broadcast
                    a = fmaf(kvr[2*c4].x, qv.x, fmaf(kvr[2*c4].y, qv.y,
                        fmaf(kvr[2*c4+1].x, qv.z, fmaf(kvr[2*c4+1].y, qv.w, a))));
                }
                part[p1_q][h][p1_sl] = a;
            }
        }
        __syncthreads();

        // ---- reduce + mask + exp + unmasked-out; lsum in register ----
        {
            const float pm = pmask[b * S_ + s0 + rd_s];
            float d = 0.f;
            #pragma unroll
            for (int q = 0; q < 8; q++) d += part[q][rd_g][rd_s];
            __builtin_nontemporal_store(d, out_unmasked + ((size_t)b * H_ + rd_g) * S_ + s0 + rd_s);
            const float pen = (1.0f - pm) * -10000.0f;
            float p = __expf(d + pen);
            p_t[rd_s][rd_g] = p;
            lsum_reg += p;
        }
        __syncthreads();

        // ---- phase 3: ctx += p * keys (from LDS), accumulate in registers ----
        {
            const int sbase = p3_sg * 16;
            #pragma unroll
            for (int si = 0; si < 16; si++) {
                const int s = sbase + si;
                float2 kv = tile2[s][p3_c2];
                float4 pA = *(const float4*)&p_t[s][0];   // broadcast
                float4 pB = *(const float4*)&p_t[s][4];
                ctx_acc[0][0] = fmaf(pA.x, kv.x, ctx_acc[0][0]); ctx_acc[0][1] = fmaf(pA.x, kv.y, ctx_acc[0][1]);
                ctx_acc[1][0] = fmaf(pA.y, kv.x, ctx_acc[1][0]); ctx_acc[1][1] = fmaf(pA.y, kv.y, ctx_acc[1][1]);
                ctx_acc[2][0] = fmaf(pA.z, kv.x, ctx_acc[2][0]); ctx_acc[2][1] = fmaf(pA.z, kv.y, ctx_acc[2][1]);
                ctx_acc[3][0] = fmaf(pA.w, kv.x, ctx_acc[3][0]); ctx_acc[3][1] = fmaf(pA.w, kv.y, ctx_acc[3][1]);
                ctx_acc[4][0] = fmaf(pB.x, kv.x, ctx_acc[4][0]); ctx_acc[4][1] = fmaf(pB.x, kv.y, ctx_acc[4][1]);
                ctx_acc[5][0] = fmaf(pB.y, kv.x, ctx_acc[5][0]); ctx_acc[5][1] = fmaf(pB.y, kv.y, ctx_acc[5][1]);
                ctx_acc[6][0] = fmaf(pB.z, kv.x, ctx_acc[6][0]); ctx_acc[6][1] = fmaf(pB.z, kv.y, ctx_acc[6][1]);
                ctx_acc[7][0] = fmaf(pB.w, kv.x, ctx_acc[7][0]); ctx_acc[7][1] = fmaf(pB.w, kv.y, ctx_acc[7][1]);
            }
        }
    }

    // ---- epilogue: one reduction + one atomic burst per block ----
    __syncthreads();   // all phase-3 reads done; part[] reusable as scratch
    {
        float r = lsum_reg;   // thread (rd_s, rd_g) holds head rd_g, key-lane rd_s partials
        #pragma unroll
        for (int off = 16; off > 0; off >>= 1) r += __shfl_xor(r, off);
        if (rd_s == 0) atomicAdd(&lsum[b * H_ + rd_g], r);
    }
    {
        float* sc = &part[0][0][0];   // [8][256] scratch
        if (p3_sg == 1) {
            #pragma unroll
            for (int h = 0; h < H_; h++) {
                sc[h * C_ + 2 * p3_c2]     = ctx_acc[h][0];
                sc[h * C_ + 2 * p3_c2 + 1] = ctx_acc[h][1];
            }
        }
        __syncthreads();
        if (p3_sg == 0) {
            float* cb = ctxsum + (size_t)b * H_ * C_;
            #pragma unroll
            for (int h = 0; h < H_; h++) {
                atomicAdd(&cb[h * C_ + 2 * p3_c2],     ctx_acc[h][0] + sc[h * C_ + 2 * p3_c2]);
                atomicAdd(&cb[h * C_ + 2 * p3_c2 + 1], ctx_acc[h][1] + sc[h * C_ + 2 * p3_c2 + 1]);
            }
        }
    }
}

// ---------------------------------------------------------------------------
// Kernel C: ctxn = ctx/L; out[l] = Wv[l,:]·ctxn[h(l),:]; unified = Wu·out + bu
// ---------------------------------------------------------------------------
__global__ __launch_bounds__(256) void finalize(const float* __restrict__ Wv,
                                                const float* __restrict__ Wu,
                                                const float* __restrict__ bu,
                                                const float* __restrict__ lsum,
                                                const float* __restrict__ ctxsum,
                                                float* __restrict__ out_unified) {
    const int b = blockIdx.x, t = threadIdx.x;
    __shared__ float ctxn[H_ * C_];
    __shared__ float outv[LD_];
    __shared__ float linv[H_];
    if (t < H_) linv[t] = 1.0f / lsum[b * H_ + t];
    __syncthreads();
    for (int i = t; i < H_ * C_; i += 256)
        ctxn[i] = ctxsum[(size_t)b * H_ * C_ + i] * linv[i >> 8];
    __syncthreads();
    {
        const float* wr = Wv + t * C_;
        const float* cx = ctxn + (t >> 5) * C_;
        float a = 0.f;
        for (int c = 0; c < C_; c += 4) {
            float4 w = *(const float4*)(wr + c);
            float4 x = *(const float4*)(cx + c);
            a = fmaf(w.x, x.x, fmaf(w.y, x.y, fmaf(w.z, x.z, fmaf(w.w, x.w, a))));
        }
        outv[t] = a;
    }
    __syncthreads();
    {
        const float* wr = Wu + t * C_;
        float a = bu[t];
        for (int c = 0; c < C_; c += 4) {
            float4 w = *(const float4*)(wr + c);
            float4 x = *(const float4*)(outv + c);
            a = fmaf(w.x, x.x, fmaf(w.y, x.y, fmaf(w.z, x.z, fmaf(w.w, x.w, a))));
        }
        out_unified[b * LD_ + t] = a;
    }
}

extern "C" void kernel_launch(void* const* d_in, const int* in_sizes, int n_in,
                              void* d_out, int out_size, void* d_ws, size_t ws_size,
                              hipStream_t stream) {
    const float* query = (const float*)d_in[0];
    const float* keys  = (const float*)d_in[1];
    const float* pmask = (const float*)d_in[2];
    const float* Wq    = (const float*)d_in[3];
    const float* Wk    = (const float*)d_in[4];
    const float* Wv    = (const float*)d_in[5];
    const float* Wu    = (const float*)d_in[6];
    const float* bu    = (const float*)d_in[7];

    float* out          = (float*)d_out;
    float* out_unified  = out;              // 32*256 floats
    float* out_unmasked = out + B_ * LD_;   // 32*8*8192 floats
    float* ws           = (float*)d_ws;

    // zero the accumulators (ws is re-poisoned to 0xAA before every launch)
    hipMemsetAsync(ws + WS_LSUM, 0, (size_t)(B_ * H_ + B_ * H_ * C_) * sizeof(float), stream);

    proj_qk<<<B_, 256, 0, stream>>>(query, Wq, Wk, ws);

    attn_pass<<<B_ * BPB, 256, 0, stream>>>(keys, pmask, ws + WS_QK,
                                            ws + WS_LSUM, ws + WS_CTX, out_unmasked);

    finalize<<<B_, 256, 0, stream>>>(Wv, Wu, bu, ws + WS_LSUM, ws + WS_CTX, out_unified);
}